// Round 6
// baseline (758.481 us; speedup 1.0000x reference)
//
#include <hip/hip_runtime.h>
#include <hip/hip_bf16.h>

// MHA block: B=8, S=1024, H=1024, NH=16, DK=64
// d_out: out f32[8,1024,1024] (8M) then attn f32[8,16,1024,1024] (128M)

typedef __bf16 bf16;
typedef __attribute__((ext_vector_type(8))) __bf16 bf16x8;
typedef __attribute__((ext_vector_type(4))) __bf16 bf16x4;
typedef __attribute__((ext_vector_type(4))) float f32x4;

#define MFMA16(a, b, c) __builtin_amdgcn_mfma_f32_16x16x32_bf16((a), (b), (c), 0, 0, 0)

#define B_ 8
#define S_ 1024
#define NH_ 16
#define DK_ 64
#define H_ 1024

__device__ __forceinline__ void gload_lds16(const void* g, void* l) {
  __builtin_amdgcn_global_load_lds(
      (__attribute__((address_space(1))) void*)g,
      (__attribute__((address_space(3))) void*)l, 16, 0, 0);
}

// ---------------- all input converts in ONE kernel (region-branched, block-aligned) ------------
__global__ __launch_bounds__(256) void cvt_all_kern(const float* __restrict__ enc,
                                                    const float* __restrict__ wq,
                                                    const float* __restrict__ wk,
                                                    const float* __restrict__ wv,
                                                    const float* __restrict__ wo_in,
                                                    const int* __restrict__ mask,
                                                    bf16* __restrict__ enc_bf,
                                                    bf16* __restrict__ wqkv,
                                                    bf16* __restrict__ wo,
                                                    unsigned char* __restrict__ mask8) {
  int i = blockIdx.x * 256 + threadIdx.x;
  if (i < 2097152) {
    float4 v = ((const float4*)enc)[i];
    bf16x4 o;
    o[0] = (bf16)v.x; o[1] = (bf16)v.y; o[2] = (bf16)v.z; o[3] = (bf16)v.w;
    ((bf16x4*)enc_bf)[i] = o;
  } else if (i < 3145728) {
    int j = i - 2097152;
    const float* src;
    bf16* dst;
    if (j < 262144) { src = wq; dst = (bf16*)wqkv; }
    else if (j < 524288) { src = wk; dst = wqkv + 1048576; j -= 262144; }
    else if (j < 786432) { src = wv; dst = wqkv + 2097152; j -= 524288; }
    else { src = wo_in; dst = wo; j -= 786432; }
    float4 v = ((const float4*)src)[j];
    bf16x4 o;
    o[0] = (bf16)v.x; o[1] = (bf16)v.y; o[2] = (bf16)v.z; o[3] = (bf16)v.w;
    ((bf16x4*)dst)[j] = o;
  } else {
    int j = i - 3145728;
    int4 v = ((const int4*)mask)[j];
    uchar4 o;
    o.x = (unsigned char)v.x; o.y = (unsigned char)v.y;
    o.z = (unsigned char)v.z; o.w = (unsigned char)v.w;
    ((uchar4*)mask8)[j] = o;
  }
}

// ---------------- 128x128 tile bf16 GEMM, C = A * Bt^T ----------------
template <bool F32OUT>
__global__ __launch_bounds__(256) void gemm_bt_kern(const bf16* __restrict__ A,
                                                    const bf16* __restrict__ Bt,
                                                    void* __restrict__ Cout,
                                                    const float* __restrict__ resid,
                                                    int K, int ldc) {
  __shared__ bf16 As[128 * 32];  // 8KB
  __shared__ bf16 Bs[128 * 32];  // 8KB
  const int lin = blockIdx.y * gridDim.x + blockIdx.x;
  const int nwg = gridDim.x * gridDim.y;
  const int chunk = nwg >> 3;
  const int v = (lin & 7) * chunk + (lin >> 3);
  const int m0 = (v / gridDim.x) * 128, n0 = (v % gridDim.x) * 128;
  const int tid = threadIdx.x;
  const int w = tid >> 6, l = tid & 63, l15 = l & 15, lg = l >> 4;
  const int wm = w >> 1, wn = w & 1;  // 2x2 waves of 64x64

  const bf16* Ab = A + (size_t)(m0 + (tid >> 2)) * K + (tid & 3) * 8;
  const bf16* Bb = Bt + (size_t)(n0 + (tid >> 2)) * K + (tid & 3) * 8;
  char* AsB = (char*)As + tid * 16;
  char* BsB = (char*)Bs + tid * 16;

  f32x4 acc[4][4] = {};
  for (int k0 = 0; k0 < K; k0 += 32) {
    gload_lds16(Ab + k0, AsB);
    gload_lds16(Ab + (size_t)64 * K + k0, AsB + 4096);
    gload_lds16(Bb + k0, BsB);
    gload_lds16(Bb + (size_t)64 * K + k0, BsB + 4096);
    __syncthreads();
    bf16x8 af[4], bfv[4];
#pragma unroll
    for (int m = 0; m < 4; m++)
      af[m] = *(const bf16x8*)&As[(wm * 64 + m * 16 + l15) * 32 + lg * 8];
#pragma unroll
    for (int n = 0; n < 4; n++)
      bfv[n] = *(const bf16x8*)&Bs[(wn * 64 + n * 16 + l15) * 32 + lg * 8];
#pragma unroll
    for (int m = 0; m < 4; m++)
#pragma unroll
      for (int n = 0; n < 4; n++) acc[m][n] = MFMA16(af[m], bfv[n], acc[m][n]);
    __syncthreads();
  }
#pragma unroll
  for (int m = 0; m < 4; m++)
#pragma unroll
    for (int n = 0; n < 4; n++)
#pragma unroll
      for (int j = 0; j < 4; j++) {
        int row = m0 + wm * 64 + m * 16 + lg * 4 + j;
        int col = n0 + wn * 64 + n * 16 + l15;
        if constexpr (F32OUT) {
          ((float*)Cout)[(size_t)row * ldc + col] =
              acc[m][n][j] + resid[(size_t)row * ldc + col];
        } else {
          ((bf16*)Cout)[(size_t)row * ldc + col] = (bf16)acc[m][n][j];
        }
      }
}

// ---------------- V transpose: qkv V-part -> vT[(b*NH+h)*DK + d][S] ----------------
__global__ __launch_bounds__(256) void vtrans_kern(const bf16* __restrict__ qkv,
                                                   bf16* __restrict__ vT) {
  int blk = blockIdx.x;
  int st = blk & 15;
  int h = (blk >> 4) & 15;
  int b = blk >> 8;
  __shared__ bf16 t[64][65];
  int tid = threadIdx.x;
  {
    int r = tid >> 2, cb = (tid & 3) * 16;
    const bf16* src = qkv + ((size_t)(b * S_ + st * 64 + r)) * 3072 + 2048 + h * DK_ + cb;
    bf16x8 u0 = *(const bf16x8*)src;
    bf16x8 u1 = *(const bf16x8*)(src + 8);
#pragma unroll
    for (int j = 0; j < 8; j++) { t[r][cb + j] = u0[j]; t[r][cb + 8 + j] = u1[j]; }
  }
  __syncthreads();
  {
    int d = tid >> 2, sb = (tid & 3) * 16;
    bf16* dst = vT + ((size_t)((b * NH_ + h) * DK_ + d)) * S_ + st * 64 + sb;
#pragma unroll
    for (int j = 0; j < 16; j++) dst[j] = t[sb + j][d];
  }
}

// ---------------- fused attention, QBLK=64, 8 waves ----------------
// grid 2048 (B*NH*S/64), 512 thr. Wave w owns keys [w*128, w*128+128).
// Swapped QK^T: col = query = l15 (+m*16), row = key = lg*4+j (+n*16+w*128).
__global__ __launch_bounds__(512, 1) void attn_kern64(const bf16* __restrict__ qkv,
                                                      const bf16* __restrict__ vT,
                                                      const unsigned char* __restrict__ mask8,
                                                      float* __restrict__ attn_out,
                                                      bf16* __restrict__ ctx) {
  __shared__ bf16 p_lds[64 * 1024];  // 128KB; first 4KB aliased as cross-wave reduce buf
  float(*red)[64][2] = (float(*)[64][2])p_lds;

  const int vb = (blockIdx.x & 7) * 256 + (blockIdx.x >> 3);
  const int qt = vb & 15;
  const int h = (vb >> 4) & 15;
  const int b = vb >> 8;
  const int q0 = qt * 64;
  const int tid = threadIdx.x;
  const int w = tid >> 6, l = tid & 63, l15 = l & 15, lg = l >> 4;
  const int kw = w * 128;  // wave's key base

  // Q fragments (B operand): lane holds Q[q=l15(+m*16)][dk=kk*32+lg*8+e]
  const bf16* qbase = qkv + ((size_t)(b * S_ + q0)) * 3072 + h * DK_;
  bf16x8 aq[4][2];
#pragma unroll
  for (int m = 0; m < 4; m++)
#pragma unroll
    for (int kk = 0; kk < 2; kk++)
      aq[m][kk] = *(const bf16x8*)(qbase + (size_t)(m * 16 + l15) * 3072 + kk * 32 + lg * 8);

  // scores: sc[n][m][j] = S[key = kw+n*16+lg*4+j][query = m*16+l15]
  f32x4 sc[8][4] = {};
  const bf16* kbase = qkv + ((size_t)(b * S_)) * 3072 + 1024 + h * DK_;
#pragma unroll
  for (int n = 0; n < 8; n++) {
#pragma unroll
    for (int kk = 0; kk < 2; kk++) {
      bf16x8 bk = *(const bf16x8*)(kbase + (size_t)(kw + n * 16 + l15) * 3072 + kk * 32 + lg * 8);
#pragma unroll
      for (int m = 0; m < 4; m++) sc[n][m] = MFMA16(bk, aq[m][kk], sc[n][m]);
    }
  }

  // scale (log2 domain) + mask via uchar4; per-lane in-register row reduce
  const unsigned char* mbase = mask8 + (size_t)b * S_ * S_;
  const float SCL = 0.125f * 1.44269504f;  // (1/sqrt(DK)) * log2(e)
  float rmax[4] = {-3e38f, -3e38f, -3e38f, -3e38f};
#pragma unroll
  for (int m = 0; m < 4; m++) {
    int q = q0 + m * 16 + l15;
#pragma unroll
    for (int n = 0; n < 8; n++) {
      int kb = kw + n * 16 + lg * 4;
      uchar4 mv = *(const uchar4*)&mbase[(size_t)q * S_ + kb];
      unsigned char mb[4] = {mv.x, mv.y, mv.z, mv.w};
#pragma unroll
      for (int j = 0; j < 4; j++) {
        float s = sc[n][m][j] * SCL;
        if (mb[j] == 0) s = -1e9f;
        sc[n][m][j] = s;
        rmax[m] = fmaxf(rmax[m], s);
      }
    }
  }
  // reduce across lg lane groups (lanes sharing a query differ only in bits 4,5)
#pragma unroll
  for (int m = 0; m < 4; m++) {
    float v = rmax[m];
    v = fmaxf(v, __shfl_xor(v, 16));
    v = fmaxf(v, __shfl_xor(v, 32));
    rmax[m] = v;
  }
  float rsum[4] = {0.f, 0.f, 0.f, 0.f};
#pragma unroll
  for (int n = 0; n < 8; n++)
#pragma unroll
    for (int m = 0; m < 4; m++)
#pragma unroll
      for (int j = 0; j < 4; j++) {
        float e = exp2f(sc[n][m][j] - rmax[m]);
        sc[n][m][j] = e;
        rsum[m] += e;
      }
#pragma unroll
  for (int m = 0; m < 4; m++) {
    float v = rsum[m];
    v += __shfl_xor(v, 16);
    v += __shfl_xor(v, 32);
    rsum[m] = v;
  }
  if (lg == 0) {
#pragma unroll
    for (int m = 0; m < 4; m++) {
      red[w][m * 16 + l15][0] = rmax[m];
      red[w][m * 16 + l15][1] = rsum[m];
    }
  }
  __syncthreads();
  // combine across 8 waves (each owns different keys for the same 64 queries)
  float scale[4];
#pragma unroll
  for (int m = 0; m < 4; m++) {
    int q = m * 16 + l15;
    float gm = -3e38f;
#pragma unroll
    for (int i = 0; i < 8; i++) gm = fmaxf(gm, red[i][q][0]);
    float gs = 0.f;
#pragma unroll
    for (int i = 0; i < 8; i++) gs += red[i][q][1] * exp2f(red[i][q][0] - gm);
    scale[m] = exp2f(rmax[m] - gm) / gs;
  }
  __syncthreads();  // red reads done before p_lds writes (aliased)

  // write attn f32 (nontemporal f32x4) + swizzled bf16x4 P into LDS
  float* arow = attn_out + ((size_t)(b * NH_ + h) * S_ + q0) * S_;
#pragma unroll
  for (int m = 0; m < 4; m++) {
    int ql = m * 16 + l15;
#pragma unroll
    for (int n = 0; n < 8; n++) {
      int kb = kw + n * 16 + lg * 4;
      f32x4 p4;
      bf16x4 pb;
#pragma unroll
      for (int j = 0; j < 4; j++) {
        float p = sc[n][m][j] * scale[m];
        p4[j] = p;
        pb[j] = (bf16)p;
      }
      __builtin_nontemporal_store(p4, (f32x4*)&arow[(size_t)ql * S_ + kb]);
      *(bf16x4*)&p_lds[ql * 1024 + (kb ^ ((ql & 7) << 3))] = pb;
    }
  }
  __syncthreads();

  // PV: wave w -> q-half (w>>2)*32, dk cols (w&3)*16 .. +16
  const int qh = (w >> 2) * 32;
  const int dkc = (w & 3) * 16;
  f32x4 o[2] = {};
  const bf16* vbase = vT + ((size_t)((b * NH_ + h) * DK_ + dkc + l15)) * S_;
#pragma unroll 8
  for (int ks = 0; ks < 32; ks++) {
    bf16x8 bv = *(const bf16x8*)(vbase + ks * 32 + lg * 8);
#pragma unroll
    for (int m2 = 0; m2 < 2; m2++) {
      int r = qh + m2 * 16 + l15;
      int e = (ks * 32 + lg * 8) ^ ((r & 7) << 3);
      bf16x8 pa = *(const bf16x8*)&p_lds[r * 1024 + e];
      o[m2] = MFMA16(pa, bv, o[m2]);
    }
  }
#pragma unroll
  for (int m2 = 0; m2 < 2; m2++)
#pragma unroll
    for (int j = 0; j < 4; j++) {
      int r = qh + m2 * 16 + lg * 4 + j;
      ctx[((size_t)(b * S_ + q0 + r)) * H_ + h * DK_ + dkc + l15] = (bf16)o[m2][j];
    }
}

// ---------------- in-place LayerNorm over last dim (1024) ----------------
__global__ __launch_bounds__(256) void ln_kern(float* __restrict__ y,
                                               const float* __restrict__ gamma,
                                               const float* __restrict__ beta) {
  int row = blockIdx.x;
  int tid = threadIdx.x;
  float4 v = *(const float4*)&y[(size_t)row * 1024 + tid * 4];
  float s = v.x + v.y + v.z + v.w;
  float q = v.x * v.x + v.y * v.y + v.z * v.z + v.w * v.w;
#pragma unroll
  for (int m = 1; m < 64; m <<= 1) { s += __shfl_xor(s, m); q += __shfl_xor(q, m); }
  __shared__ float rb[8];
  if ((tid & 63) == 0) { rb[(tid >> 6) * 2] = s; rb[(tid >> 6) * 2 + 1] = q; }
  __syncthreads();
  s = rb[0] + rb[2] + rb[4] + rb[6];
  q = rb[1] + rb[3] + rb[5] + rb[7];
  float mu = s * (1.f / 1024.f);
  float var = q * (1.f / 1024.f) - mu * mu;
  float rstd = rsqrtf(var + 1e-6f);
  float4 g = *(const float4*)&gamma[tid * 4];
  float4 bb = *(const float4*)&beta[tid * 4];
  float4 o;
  o.x = (v.x - mu) * rstd * g.x + bb.x;
  o.y = (v.y - mu) * rstd * g.y + bb.y;
  o.z = (v.z - mu) * rstd * g.z + bb.z;
  o.w = (v.w - mu) * rstd * g.w + bb.w;
  *(float4*)&y[(size_t)row * 1024 + tid * 4] = o;
}

extern "C" void kernel_launch(void* const* d_in, const int* in_sizes, int n_in,
                              void* d_out, int out_size, void* d_ws, size_t ws_size,
                              hipStream_t stream) {
  const float* enc = (const float*)d_in[0];
  const int* mask = (const int*)d_in[1];
  const float* W_Q = (const float*)d_in[2];
  const float* W_K = (const float*)d_in[3];
  const float* W_V = (const float*)d_in[4];
  const float* W_O = (const float*)d_in[5];
  const float* ln_g = (const float*)d_in[6];
  const float* ln_b = (const float*)d_in[7];

  float* out_f32 = (float*)d_out;                          // [8192][1024]
  float* attn_f32 = (float*)d_out + (size_t)B_ * S_ * H_;  // [128][1024][1024]

  // ws layout (bytes): enc_bf 16M | wqkv 6M | wo 2M | qkv 48M | vT 16M | ctx 16M | mask8 8M
  char* wsb = (char*)d_ws;
  bf16* enc_bf = (bf16*)wsb;
  bf16* wqkv = (bf16*)(wsb + 16777216);
  bf16* wo = (bf16*)(wsb + 23068672);
  bf16* qkv = (bf16*)(wsb + 25165824);
  bf16* vT = (bf16*)(wsb + 75497472);
  bf16* ctx = (bf16*)(wsb + 92274688);
  unsigned char* mask8 = (unsigned char*)(wsb + 109051904);

  // 1) all converts in one launch (enc, 4 weights, mask)
  cvt_all_kern<<<20480, 256, 0, stream>>>(enc, W_Q, W_K, W_V, W_O, mask,
                                          enc_bf, wqkv, wo, mask8);

  // 2) QKV projection: [8192,1024] x [3072,1024]^T -> qkv bf16 [8192][3072]
  gemm_bt_kern<false><<<dim3(24, 64), 256, 0, stream>>>(enc_bf, wqkv, qkv, nullptr, 1024, 3072);

  // 3) V transpose -> vT
  vtrans_kern<<<2048, 256, 0, stream>>>(qkv, vT);

  // 4) fused attention (+ writes attn_dist output)
  attn_kern64<<<2048, 512, 0, stream>>>(qkv, vT, mask8, attn_f32, ctx);
  // PROBE: duplicate launch (idempotent — writes identical bytes). dur = base + 2*attn.
  // Next round drops this to read attn's standalone time from the delta.
  attn_kern64<<<2048, 512, 0, stream>>>(qkv, vT, mask8, attn_f32, ctx);

  // 5) output projection + residual -> d_out (pre-LN f32)
  gemm_bt_kern<true><<<dim3(8, 64), 256, 0, stream>>>(ctx, wo, out_f32, enc, 1024, 1024);

  // 6) in-place LayerNorm
  ln_kern<<<8192, 256, 0, stream>>>(out_f32, ln_g, ln_b);
}

// Round 8
// 296.919 us; speedup vs baseline: 2.5545x; 2.5545x over previous
//
#include <hip/hip_runtime.h>
#include <hip/hip_bf16.h>

// MHA block: B=8, S=1024, H=1024, NH=16, DK=64
// d_out: out f32[8,1024,1024] (8M) then attn f32[8,16,1024,1024] (128M)

typedef __bf16 bf16;
typedef __attribute__((ext_vector_type(8))) __bf16 bf16x8;
typedef __attribute__((ext_vector_type(4))) __bf16 bf16x4;
typedef __attribute__((ext_vector_type(4))) float f32x4;

#define MFMA16(a, b, c) __builtin_amdgcn_mfma_f32_16x16x32_bf16((a), (b), (c), 0, 0, 0)

#define B_ 8
#define S_ 1024
#define NH_ 16
#define DK_ 64
#define H_ 1024

__device__ __forceinline__ void gload_lds16b(const void* g, void* l) {
  __builtin_amdgcn_global_load_lds(
      (__attribute__((address_space(1))) void*)g,
      (__attribute__((address_space(3))) void*)l, 16, 0, 0);
}

__device__ __forceinline__ bf16x8 cat8(bf16x4 a, bf16x4 b) {
  bf16x8 r;
  r[0] = a[0]; r[1] = a[1]; r[2] = a[2]; r[3] = a[3];
  r[4] = b[0]; r[5] = b[1]; r[6] = b[2]; r[7] = b[3];
  return r;
}

// ---------------- all input converts in ONE kernel ----------------
__global__ __launch_bounds__(256) void cvt_all_kern(const float* __restrict__ enc,
                                                    const float* __restrict__ wq,
                                                    const float* __restrict__ wk,
                                                    const float* __restrict__ wv,
                                                    const float* __restrict__ wo_in,
                                                    const int* __restrict__ mask,
                                                    bf16* __restrict__ enc_bf,
                                                    bf16* __restrict__ wqkv,
                                                    bf16* __restrict__ wo,
                                                    unsigned char* __restrict__ mask8) {
  int i = blockIdx.x * 256 + threadIdx.x;
  if (i < 2097152) {
    float4 v = ((const float4*)enc)[i];
    bf16x4 o;
    o[0] = (bf16)v.x; o[1] = (bf16)v.y; o[2] = (bf16)v.z; o[3] = (bf16)v.w;
    ((bf16x4*)enc_bf)[i] = o;
  } else if (i < 3145728) {
    int j = i - 2097152;
    const float* src;
    bf16* dst;
    if (j < 262144) { src = wq; dst = (bf16*)wqkv; }
    else if (j < 524288) { src = wk; dst = wqkv + 1048576; j -= 262144; }
    else if (j < 786432) { src = wv; dst = wqkv + 2097152; j -= 524288; }
    else { src = wo_in; dst = wo; j -= 786432; }
    float4 v = ((const float4*)src)[j];
    bf16x4 o;
    o[0] = (bf16)v.x; o[1] = (bf16)v.y; o[2] = (bf16)v.z; o[3] = (bf16)v.w;
    ((bf16x4*)dst)[j] = o;
  } else {
    int j = i - 3145728;
    int4 v = ((const int4*)mask)[j];
    uchar4 o;
    o.x = (unsigned char)v.x; o.y = (unsigned char)v.y;
    o.z = (unsigned char)v.z; o.w = (unsigned char)v.w;
    ((uchar4*)mask8)[j] = o;
  }
}

// ---------------- 128x128 tile bf16 GEMM, C = A * Bt^T ----------------
template <bool F32OUT>
__global__ __launch_bounds__(256) void gemm_bt_kern(const bf16* __restrict__ A,
                                                    const bf16* __restrict__ Bt,
                                                    void* __restrict__ Cout,
                                                    const float* __restrict__ resid,
                                                    int K, int ldc) {
  __shared__ bf16 As[128 * 32];
  __shared__ bf16 Bs[128 * 32];
  const int lin = blockIdx.y * gridDim.x + blockIdx.x;
  const int nwg = gridDim.x * gridDim.y;
  const int chunk = nwg >> 3;
  const int v = (lin & 7) * chunk + (lin >> 3);
  const int m0 = (v / gridDim.x) * 128, n0 = (v % gridDim.x) * 128;
  const int tid = threadIdx.x;
  const int w = tid >> 6, l = tid & 63, l15 = l & 15, lg = l >> 4;
  const int wm = w >> 1, wn = w & 1;

  const bf16* Ab = A + (size_t)(m0 + (tid >> 2)) * K + (tid & 3) * 8;
  const bf16* Bb = Bt + (size_t)(n0 + (tid >> 2)) * K + (tid & 3) * 8;
  char* AsB = (char*)As + tid * 16;
  char* BsB = (char*)Bs + tid * 16;

  f32x4 acc[4][4] = {};
  for (int k0 = 0; k0 < K; k0 += 32) {
    gload_lds16b(Ab + k0, AsB);
    gload_lds16b(Ab + (size_t)64 * K + k0, AsB + 4096);
    gload_lds16b(Bb + k0, BsB);
    gload_lds16b(Bb + (size_t)64 * K + k0, BsB + 4096);
    __syncthreads();
    bf16x8 af[4], bfv[4];
#pragma unroll
    for (int m = 0; m < 4; m++)
      af[m] = *(const bf16x8*)&As[(wm * 64 + m * 16 + l15) * 32 + lg * 8];
#pragma unroll
    for (int n = 0; n < 4; n++)
      bfv[n] = *(const bf16x8*)&Bs[(wn * 64 + n * 16 + l15) * 32 + lg * 8];
#pragma unroll
    for (int m = 0; m < 4; m++)
#pragma unroll
      for (int n = 0; n < 4; n++) acc[m][n] = MFMA16(af[m], bfv[n], acc[m][n]);
    __syncthreads();
  }
#pragma unroll
  for (int m = 0; m < 4; m++)
#pragma unroll
    for (int n = 0; n < 4; n++)
#pragma unroll
      for (int j = 0; j < 4; j++) {
        int row = m0 + wm * 64 + m * 16 + lg * 4 + j;
        int col = n0 + wn * 64 + n * 16 + l15;
        if constexpr (F32OUT) {
          ((float*)Cout)[(size_t)row * ldc + col] =
              acc[m][n][j] + resid[(size_t)row * ldc + col];
        } else {
          ((bf16*)Cout)[(size_t)row * ldc + col] = (bf16)acc[m][n][j];
        }
      }
}

// ---------------- V transpose: qkv V-part -> vT[(b*NH+h)*DK + d][S] ----------------
__global__ __launch_bounds__(256) void vtrans_kern(const bf16* __restrict__ qkv,
                                                   bf16* __restrict__ vT) {
  int blk = blockIdx.x;
  int st = blk & 15;
  int h = (blk >> 4) & 15;
  int b = blk >> 8;
  __shared__ bf16 t[64][65];
  int tid = threadIdx.x;
  {
    int r = tid >> 2, cb = (tid & 3) * 16;
    const bf16* src = qkv + ((size_t)(b * S_ + st * 64 + r)) * 3072 + 2048 + h * DK_ + cb;
    bf16x8 u0 = *(const bf16x8*)src;
    bf16x8 u1 = *(const bf16x8*)(src + 8);
#pragma unroll
    for (int j = 0; j < 8; j++) { t[r][cb + j] = u0[j]; t[r][cb + 8 + j] = u1[j]; }
  }
  __syncthreads();
  {
    int d = tid >> 2, sb = (tid & 3) * 16;
    bf16* dst = vT + ((size_t)((b * NH_ + h) * DK_ + d)) * S_ + st * 64 + sb;
#pragma unroll
    for (int j = 0; j < 16; j++) dst[j] = t[sb + j][d];
  }
}

// ---------------- fused attention: LDS-staged, coalesced-global, padded-LDS ----------------
// QBLK=32, 512 thr (8 waves), 2 blocks/CU. Wave w: ksub=w&3 (key subtile), qsub=w>>2 (q half).
// All global loads linear+coalesced; fragment divergence served from +8B-padded LDS rows.
// LDS: P [32 q][2056B] (mask [32][1032B] aliased first) | stage [64][136B] | qtile [32][136B]/red
#define PSTR 2056
#define MSTR 1032
#define KSTR 136

__global__ __launch_bounds__(512, 2) void attn_fused(const bf16* __restrict__ qkv,
                                                     const bf16* __restrict__ vT,
                                                     const unsigned char* __restrict__ mask8,
                                                     float* __restrict__ attn_out,
                                                     bf16* __restrict__ ctx) {
  __shared__ char smem[78848];
  char* Pb = smem;                      // 65792 B
  char* stg = smem + 65792;             // 8704 B
  char* qtl = smem + 74496;             // 4352 B
  float* red = (float*)(smem + 74496);  // [8][32][2] f32, alias qtl (Q consumed first)

  const int vb = (blockIdx.x & 7) * 512 + (blockIdx.x >> 3);
  const int qt = vb & 31, h = (vb >> 5) & 15, b = vb >> 9;
  const int q0 = qt * 32;
  const int t = threadIdx.x;
  const int w = t >> 6, l = t & 63, l15 = l & 15, lg = l >> 4;
  const int qsub = w >> 2, ksub = w & 3;
  const int qrow = qsub * 16 + l15;  // lane's q row (0..31)

  const char* qkv_b = (const char*)qkv;
  const char* kb_g = qkv_b + (size_t)b * S_ * 6144 + 2048 + (size_t)h * 128;
  const char* vT_b = (const char*)vT + (size_t)(b * NH_ + h) * 64 * 2048;
  const unsigned char* mrow = mask8 + (size_t)b * S_ * S_ + (size_t)q0 * S_;

  // stage-thread geometry (shared by K/V chunks): row = t>>3 (64 rows), col = (t&7)*16
  const int srow = t >> 3, scol = (t & 7) * 16;

  // ---- prologue: issue Q + mask + K0/K1 loads (all linear coalesced) ----
  uint4 qreg, mreg[4], kr0, kr1;
  if (t < 256) {
    int row = t >> 3;
    qreg = *(const uint4*)(qkv_b + (size_t)(b * S_ + q0 + row) * 6144 + h * 128 + scol);
  }
#pragma unroll
  for (int p = 0; p < 4; p++) {
    int row = (t >> 6) + p * 8, col = (t & 63) * 16;
    mreg[p] = *(const uint4*)(mrow + (size_t)row * 1024 + col);
  }
  kr0 = *(const uint4*)(kb_g + (size_t)srow * 6144 + scol);
  kr1 = *(const uint4*)(kb_g + (size_t)(64 + srow) * 6144 + scol);

  // write Q, mask, K0
  if (t < 256) {
    int row = t >> 3;
    *(uint2*)(qtl + row * KSTR + scol) = make_uint2(qreg.x, qreg.y);
    *(uint2*)(qtl + row * KSTR + scol + 8) = make_uint2(qreg.z, qreg.w);
  }
#pragma unroll
  for (int p = 0; p < 4; p++) {
    int row = (t >> 6) + p * 8, col = (t & 63) * 16;
    *(uint2*)(Pb + row * MSTR + col) = make_uint2(mreg[p].x, mreg[p].y);
    *(uint2*)(Pb + row * MSTR + col + 8) = make_uint2(mreg[p].z, mreg[p].w);
  }
  *(uint2*)(stg + srow * KSTR + scol) = make_uint2(kr0.x, kr0.y);
  *(uint2*)(stg + srow * KSTR + scol + 8) = make_uint2(kr0.z, kr0.w);
  __syncthreads();

  // Q fragments (B operand): lane holds Q[q=qrow][dk=kk*32+lg*8..+7]
  bf16x8 aq[2];
#pragma unroll
  for (int kk = 0; kk < 2; kk++) {
    bf16x4 a0 = *(bf16x4*)(qtl + qrow * KSTR + kk * 64 + lg * 16);
    bf16x4 a1 = *(bf16x4*)(qtl + qrow * KSTR + kk * 64 + lg * 16 + 8);
    aq[kk] = cat8(a0, a1);
  }

  // ---- QK^T over 16 chunks of 64 keys, depth-2 reg prefetch ----
  f32x4 sc[16];
#pragma unroll
  for (int i = 0; i < 16; i++) sc[i] = (f32x4){0.f, 0.f, 0.f, 0.f};
  uint4 kr[2];
  kr[1] = kr1;
  const int krow = ksub * 16 + l15;  // A-operand key row within chunk
#pragma unroll
  for (int cc = 0; cc < 16; cc++) {
    if (cc < 14)
      kr[cc & 1] = *(const uint4*)(kb_g + (size_t)((cc + 2) * 64 + srow) * 6144 + scol);
#pragma unroll
    for (int kk = 0; kk < 2; kk++) {
      bf16x4 b0 = *(bf16x4*)(stg + krow * KSTR + kk * 64 + lg * 16);
      bf16x4 b1 = *(bf16x4*)(stg + krow * KSTR + kk * 64 + lg * 16 + 8);
      sc[cc] = MFMA16(cat8(b0, b1), aq[kk], sc[cc]);
    }
    __syncthreads();
    if (cc < 15) {
      uint4 kw = kr[(cc + 1) & 1];
      *(uint2*)(stg + srow * KSTR + scol) = make_uint2(kw.x, kw.y);
      *(uint2*)(stg + srow * KSTR + scol + 8) = make_uint2(kw.z, kw.w);
    }
    __syncthreads();
  }

  // ---- mask + scale + exp (log2 domain) + row reduce ----
  const float SCL = 0.125f * 1.44269504f;
  float rmax = -3e38f;
#pragma unroll
  for (int cc = 0; cc < 16; cc++) {
    int kb4 = cc * 64 + ksub * 16 + lg * 4;
    uchar4 mv = *(const uchar4*)(Pb + qrow * MSTR + kb4);
    unsigned char mb[4] = {mv.x, mv.y, mv.z, mv.w};
#pragma unroll
    for (int j = 0; j < 4; j++) {
      float s = sc[cc][j] * SCL;
      if (mb[j] == 0) s = -1e9f;
      sc[cc][j] = s;
      rmax = fmaxf(rmax, s);
    }
  }
  rmax = fmaxf(rmax, __shfl_xor(rmax, 16));
  rmax = fmaxf(rmax, __shfl_xor(rmax, 32));
  float rsum = 0.f;
#pragma unroll
  for (int cc = 0; cc < 16; cc++)
#pragma unroll
    for (int j = 0; j < 4; j++) {
      float e = exp2f(sc[cc][j] - rmax);
      sc[cc][j] = e;
      rsum += e;
    }
  rsum += __shfl_xor(rsum, 16);
  rsum += __shfl_xor(rsum, 32);
  if (lg == 0) {
    red[(w * 32 + qrow) * 2] = rmax;
    red[(w * 32 + qrow) * 2 + 1] = rsum;
  }
  __syncthreads();  // mask reads done; red ready
  float gm = -3e38f, gs = 0.f;
  const int g4 = qsub * 4;
#pragma unroll
  for (int i = 0; i < 4; i++) gm = fmaxf(gm, red[((g4 + i) * 32 + qrow) * 2]);
#pragma unroll
  for (int i = 0; i < 4; i++)
    gs += red[((g4 + i) * 32 + qrow) * 2 + 1] * exp2f(red[((g4 + i) * 32 + qrow) * 2] - gm);
  const float scale = exp2f(rmax - gm) / gs;

  // ---- P (bf16, scaled) into padded LDS ----
#pragma unroll
  for (int cc = 0; cc < 16; cc++) {
    bf16x4 pb;
#pragma unroll
    for (int j = 0; j < 4; j++) pb[j] = (bf16)(sc[cc][j] * scale);
    *(bf16x4*)(Pb + qrow * PSTR + cc * 128 + ksub * 32 + lg * 8) = pb;
  }
  // issue V0/V1 loads (stage free since QK done)
  uint4 vr[2];
  vr[0] = *(const uint4*)(vT_b + (size_t)srow * 2048 + scol);
  vr[1] = *(const uint4*)(vT_b + (size_t)srow * 2048 + 128 + scol);
  __syncthreads();  // P visible to all
  // write V0
  *(uint2*)(stg + srow * KSTR + scol) = make_uint2(vr[0].x, vr[0].y);
  *(uint2*)(stg + srow * KSTR + scol + 8) = make_uint2(vr[0].z, vr[0].w);

  // ---- attn_dist writeback: coalesced f32 from P LDS ----
  {
    int row = t >> 4, c16 = t & 15;
    float* arow = attn_out + (size_t)((b * NH_ + h) * S_ + q0 + row) * S_;
#pragma unroll
    for (int it = 0; it < 16; it++) {
      bf16x4 pv = *(bf16x4*)(Pb + row * PSTR + c16 * 8 + it * 128);
      f32x4 o4;
#pragma unroll
      for (int j = 0; j < 4; j++) o4[j] = (float)pv[j];
      __builtin_nontemporal_store(o4, (f32x4*)(arow + c16 * 4 + it * 64));
    }
  }
  __syncthreads();  // V0 staged

  // ---- PV over 16 chunks of 64 kv, depth-2 reg prefetch ----
  f32x4 o = {0.f, 0.f, 0.f, 0.f};
  const int dkr = ksub * 16 + l15;  // V-tile dk row
#pragma unroll
  for (int cc = 0; cc < 16; cc++) {
    if (cc < 14)
      vr[cc & 1] = *(const uint4*)(vT_b + (size_t)srow * 2048 + (cc + 2) * 128 + scol);
#pragma unroll
    for (int tt = 0; tt < 2; tt++) {
      bf16x4 p0 = *(bf16x4*)(Pb + qrow * PSTR + cc * 128 + tt * 64 + lg * 16);
      bf16x4 p1 = *(bf16x4*)(Pb + qrow * PSTR + cc * 128 + tt * 64 + lg * 16 + 8);
      bf16x4 v0 = *(bf16x4*)(stg + dkr * KSTR + tt * 64 + lg * 16);
      bf16x4 v1 = *(bf16x4*)(stg + dkr * KSTR + tt * 64 + lg * 16 + 8);
      o = MFMA16(cat8(p0, p1), cat8(v0, v1), o);
    }
    __syncthreads();
    if (cc < 15) {
      uint4 vw = vr[(cc + 1) & 1];
      *(uint2*)(stg + srow * KSTR + scol) = make_uint2(vw.x, vw.y);
      *(uint2*)(stg + srow * KSTR + scol + 8) = make_uint2(vw.z, vw.w);
    }
    __syncthreads();
  }

  // ---- ctx: via LDS tile for coalesced store ----
#pragma unroll
  for (int jj = 0; jj < 4; jj++) {
    int row = qsub * 16 + lg * 4 + jj;
    *(bf16*)(stg + row * KSTR + (ksub * 16 + l15) * 2) = (bf16)o[jj];
  }
  __syncthreads();
  if (t < 256) {
    int row = t >> 3;
    bf16x4 c0 = *(bf16x4*)(stg + row * KSTR + scol);
    bf16x4 c1 = *(bf16x4*)(stg + row * KSTR + scol + 8);
    bf16x8 cv = cat8(c0, c1);
    *(bf16x8*)((char*)ctx + (size_t)(b * S_ + q0 + row) * 2048 + h * 128 + scol) = cv;
  }
}

// ---------------- in-place LayerNorm over last dim (1024) ----------------
__global__ __launch_bounds__(256) void ln_kern(float* __restrict__ y,
                                               const float* __restrict__ gamma,
                                               const float* __restrict__ beta) {
  int row = blockIdx.x;
  int tid = threadIdx.x;
  float4 v = *(const float4*)&y[(size_t)row * 1024 + tid * 4];
  float s = v.x + v.y + v.z + v.w;
  float q = v.x * v.x + v.y * v.y + v.z * v.z + v.w * v.w;
#pragma unroll
  for (int m = 1; m < 64; m <<= 1) { s += __shfl_xor(s, m); q += __shfl_xor(q, m); }
  __shared__ float rb[8];
  if ((tid & 63) == 0) { rb[(tid >> 6) * 2] = s; rb[(tid >> 6) * 2 + 1] = q; }
  __syncthreads();
  s = rb[0] + rb[2] + rb[4] + rb[6];
  q = rb[1] + rb[3] + rb[5] + rb[7];
  float mu = s * (1.f / 1024.f);
  float var = q * (1.f / 1024.f) - mu * mu;
  float rstd = rsqrtf(var + 1e-6f);
  float4 g = *(const float4*)&gamma[tid * 4];
  float4 bb = *(const float4*)&beta[tid * 4];
  float4 o;
  o.x = (v.x - mu) * rstd * g.x + bb.x;
  o.y = (v.y - mu) * rstd * g.y + bb.y;
  o.z = (v.z - mu) * rstd * g.z + bb.z;
  o.w = (v.w - mu) * rstd * g.w + bb.w;
  *(float4*)&y[(size_t)row * 1024 + tid * 4] = o;
}

extern "C" void kernel_launch(void* const* d_in, const int* in_sizes, int n_in,
                              void* d_out, int out_size, void* d_ws, size_t ws_size,
                              hipStream_t stream) {
  const float* enc = (const float*)d_in[0];
  const int* mask = (const int*)d_in[1];
  const float* W_Q = (const float*)d_in[2];
  const float* W_K = (const float*)d_in[3];
  const float* W_V = (const float*)d_in[4];
  const float* W_O = (const float*)d_in[5];
  const float* ln_g = (const float*)d_in[6];
  const float* ln_b = (const float*)d_in[7];

  float* out_f32 = (float*)d_out;                          // [8192][1024]
  float* attn_f32 = (float*)d_out + (size_t)B_ * S_ * H_;  // [128][1024][1024]

  // ws layout (bytes): enc_bf 16M | wqkv 6M | wo 2M | qkv 48M | vT 16M | ctx 16M | mask8 8M
  char* wsb = (char*)d_ws;
  bf16* enc_bf = (bf16*)wsb;
  bf16* wqkv = (bf16*)(wsb + 16777216);
  bf16* wo = (bf16*)(wsb + 23068672);
  bf16* qkv = (bf16*)(wsb + 25165824);
  bf16* vT = (bf16*)(wsb + 75497472);
  bf16* ctx = (bf16*)(wsb + 92274688);
  unsigned char* mask8 = (unsigned char*)(wsb + 109051904);

  // 1) all converts in one launch
  cvt_all_kern<<<20480, 256, 0, stream>>>(enc, W_Q, W_K, W_V, W_O, mask,
                                          enc_bf, wqkv, wo, mask8);

  // 2) QKV projection
  gemm_bt_kern<false><<<dim3(24, 64), 256, 0, stream>>>(enc_bf, wqkv, qkv, nullptr, 1024, 3072);

  // 3) V transpose
  vtrans_kern<<<2048, 256, 0, stream>>>(qkv, vT);

  // 4) fused attention (+ attn_dist output)
  attn_fused<<<4096, 512, 0, stream>>>(qkv, vT, mask8, attn_f32, ctx);

  // 5) output projection + residual
  gemm_bt_kern<true><<<dim3(8, 64), 256, 0, stream>>>(ctx, wo, out_f32, enc, 1024, 1024);

  // 6) in-place LayerNorm
  ln_kern<<<8192, 256, 0, stream>>>(out_f32, ln_g, ln_b);
}